// Round 1
// baseline (18988.002 us; speedup 1.0000x reference)
//
#include <hip/hip_runtime.h>

#define DEVI __device__ __forceinline__

typedef __attribute__((ext_vector_type(8))) __bf16 bf16x8;
typedef __attribute__((ext_vector_type(4))) float f32x4;

// ---------- scalar helpers ----------
DEVI unsigned short f2b(float f) {           // f32 -> bf16 (RNE)
  unsigned u = __float_as_uint(f);
  u = u + 0x7fffu + ((u >> 16) & 1u);
  return (unsigned short)(u >> 16);
}
DEVI float b2f(unsigned short h) { return __uint_as_float(((unsigned)h) << 16); }
DEVI float lo16(unsigned u) { return __uint_as_float(u << 16); }            // low bf16 of packed pair
DEVI float hi16(unsigned u) { return __uint_as_float(u & 0xffff0000u); }    // high bf16
DEVI float sigm(float x) { return 1.f / (1.f + __expf(-x)); }

// ---------- prep kernels ----------
__global__ void cvt_bf16(const float* __restrict__ in, unsigned short* __restrict__ out, int n) {
  for (int i = blockIdx.x * blockDim.x + threadIdx.x; i < n; i += gridDim.x * blockDim.x)
    out[i] = f2b(in[i]);
}

// Whh (2,1024,256) f32 -> packed transposed uint[2][128][1024]:
// out[d][kk][j] = (bf16(W[d][j][2kk]) , bf16(W[d][j][2kk+1]))
__global__ void whh_pack(const float* __restrict__ W, unsigned* __restrict__ out) {
  int idx = blockIdx.x * blockDim.x + threadIdx.x;   // 262144 total
  int d = idx >> 17, rem = idx & 131071, kk = rem >> 10, j = rem & 1023;
  const float* w = W + (((size_t)d * 1024 + j) * 256 + 2 * kk);
  out[idx] = (unsigned)f2b(w[0]) | ((unsigned)f2b(w[1]) << 16);
}

__global__ void bias_sum(const float* __restrict__ a, const float* __restrict__ b,
                         float* __restrict__ o, int n) {
  int i = blockIdx.x * blockDim.x + threadIdx.x;
  if (i < n) o[i] = a[i] + b[i];
}

// char embedding gather: out[bt][c] = bf16(tab[ids[bt]][c]), CE=128
__global__ void embed_gather(const int* __restrict__ ids, const float* __restrict__ tab,
                             unsigned short* __restrict__ out, int total) {
  for (int i = blockIdx.x * blockDim.x + threadIdx.x; i < total; i += gridDim.x * blockDim.x) {
    int bt = i >> 7, c = i & 127;
    out[i] = f2b(tab[(size_t)ids[bt] * 128 + c]);
  }
}

// ---------- GEMM: C[M,N] = act(A[M,K] @ W[N,K]^T + bias[N]) -> bf16 ----------
// 64x64 tile, 4 waves, mfma_f32_16x16x32_bf16, operands straight from global (L2).
template <int ACT, int AFP32>
__global__ __launch_bounds__(256) void gemm_bt(const void* __restrict__ Av,
                                               const unsigned short* __restrict__ W,
                                               const float* __restrict__ bias,
                                               unsigned short* __restrict__ C,
                                               int M, int N, int K) {
  const int ntiles = N >> 6;
  const int mt = blockIdx.x / ntiles;
  const int nt = blockIdx.x - mt * ntiles;
  const int m0 = mt << 6, n0 = nt << 6;
  const int tid = threadIdx.x;
  const int w = tid >> 6, lane = tid & 63, r = lane & 15, q = lane >> 4;
  f32x4 acc0 = {0.f, 0.f, 0.f, 0.f}, acc1 = acc0, acc2 = acc0, acc3 = acc0;
  const int arow = m0 + w * 16 + r;
  const unsigned short* Ab = (const unsigned short*)Av;
  const float* Af = (const float*)Av;
  for (int k0 = 0; k0 < K; k0 += 32) {
    const int ka = k0 + q * 8;
    bf16x8 a;
    if constexpr (AFP32) {
      const float* ap = Af + (size_t)arow * K + ka;
      float4 f0 = *(const float4*)ap;
      float4 f1 = *(const float4*)(ap + 4);
      union { unsigned short e[8]; bf16x8 v; } ua;
      ua.e[0] = f2b(f0.x); ua.e[1] = f2b(f0.y); ua.e[2] = f2b(f0.z); ua.e[3] = f2b(f0.w);
      ua.e[4] = f2b(f1.x); ua.e[5] = f2b(f1.y); ua.e[6] = f2b(f1.z); ua.e[7] = f2b(f1.w);
      a = ua.v;
    } else {
      a = *(const bf16x8*)(const void*)(Ab + (size_t)arow * K + ka);
    }
    const unsigned short* wb = W + (size_t)(n0 + r) * K + ka;
    bf16x8 b0 = *(const bf16x8*)(const void*)(wb);
    bf16x8 b1 = *(const bf16x8*)(const void*)(wb + (size_t)16 * K);
    bf16x8 b2 = *(const bf16x8*)(const void*)(wb + (size_t)32 * K);
    bf16x8 b3 = *(const bf16x8*)(const void*)(wb + (size_t)48 * K);
    acc0 = __builtin_amdgcn_mfma_f32_16x16x32_bf16(a, b0, acc0, 0, 0, 0);
    acc1 = __builtin_amdgcn_mfma_f32_16x16x32_bf16(a, b1, acc1, 0, 0, 0);
    acc2 = __builtin_amdgcn_mfma_f32_16x16x32_bf16(a, b2, acc2, 0, 0, 0);
    acc3 = __builtin_amdgcn_mfma_f32_16x16x32_bf16(a, b3, acc3, 0, 0, 0);
  }
  // D layout (m89-verified): col = lane&15, row = (lane>>4)*4 + reg
  const int rbase = m0 + w * 16 + q * 4;
  #pragma unroll
  for (int nb = 0; nb < 4; ++nb) {
    f32x4 acc = nb == 0 ? acc0 : nb == 1 ? acc1 : nb == 2 ? acc2 : acc3;
    const int col = n0 + nb * 16 + r;
    const float bv = bias[col];
    #pragma unroll
    for (int i = 0; i < 4; ++i) {
      float v = acc[i] + bv;
      if constexpr (ACT) v = fmaxf(v, 0.f);
      C[(size_t)(rbase + i) * N + col] = f2b(v);
    }
  }
}

// ---------- LSTM recurrence: one workgroup per (sample, direction) ----------
// xg layout: [B][T][2048] bf16, col = dir*1024 + gate*256 + u (gate order i,f,g,o)
// W2: packed uint [2][128][1024]; thread u owns hidden unit u (all 4 gates -> local c,h).
__global__ __launch_bounds__(256) void lstm_rec(const unsigned* __restrict__ W2,
                                                const unsigned short* __restrict__ xg,
                                                unsigned short* __restrict__ out,
                                                const int outStride, const int outOff,
                                                const int T) {
  const int b = blockIdx.x >> 1, dir = blockIdx.x & 1;
  const int u = threadIdx.x;
  __shared__ float hs[256];
  hs[u] = 0.f;
  float c = 0.f;
  const unsigned* Wb = W2 + (size_t)dir * 131072 + u;
  const unsigned short* xb = xg + (size_t)b * T * 2048 + dir * 1024 + u;
  unsigned short* ob = out + (size_t)b * T * outStride + outOff + dir * 256 + u;
  __syncthreads();
  for (int ti = 0; ti < T; ++ti) {
    const int t = dir ? (T - 1 - ti) : ti;
    const unsigned short* x = xb + (size_t)t * 2048;
    float gi = b2f(x[0]), gf = b2f(x[256]), gg = b2f(x[512]), go = b2f(x[768]);
    const unsigned* wp = Wb;
    #pragma unroll 8
    for (int kk = 0; kk < 128; ++kk) {
      const float2 h2 = *(const float2*)&hs[kk * 2];   // broadcast, conflict-free
      const unsigned wi = wp[0], wf = wp[256], wg = wp[512], wo = wp[768];
      gi = fmaf(h2.x, lo16(wi), gi); gi = fmaf(h2.y, hi16(wi), gi);
      gf = fmaf(h2.x, lo16(wf), gf); gf = fmaf(h2.y, hi16(wf), gf);
      gg = fmaf(h2.x, lo16(wg), gg); gg = fmaf(h2.y, hi16(wg), gg);
      go = fmaf(h2.x, lo16(wo), go); go = fmaf(h2.y, hi16(wo), go);
      wp += 1024;
    }
    c = sigm(gf) * c + sigm(gi) * tanhf(gg);
    const float h = sigm(go) * tanhf(c);
    __syncthreads();          // all reads of old hs done
    hs[u] = h;
    __syncthreads();          // new hs visible
    ob[(size_t)t * outStride] = f2b(h);
  }
}

// ---------- classifier layer 2: logits[M,15] (stride 16) = h1[M,512] @ w2[15,512]^T + b2 ----------
__global__ __launch_bounds__(256) void cls2_kernel(const unsigned short* __restrict__ h1,
                                                   const unsigned short* __restrict__ w2,
                                                   const float* __restrict__ b2,
                                                   float* __restrict__ logits, int M) {
  int idx = blockIdx.x * 256 + threadIdx.x;
  int row = idx >> 4, n = idx & 15;
  if (row >= M || n >= 15) return;
  const unsigned* hp = (const unsigned*)(h1 + (size_t)row * 512);
  const unsigned* wp = (const unsigned*)(w2 + (size_t)n * 512);
  float acc = 0.f;
  #pragma unroll 8
  for (int k = 0; k < 256; ++k) {
    unsigned uh = hp[k], uw = wp[k];
    acc = fmaf(lo16(uh), lo16(uw), acc);
    acc = fmaf(hi16(uh), hi16(uw), acc);
  }
  logits[(size_t)row * 16 + n] = acc + b2[n];
}

// ---------- CRF ----------
__global__ void crf_num(const float* __restrict__ logits, const int* __restrict__ tags,
                        const float* __restrict__ start, const float* __restrict__ end,
                        const float* __restrict__ trans, float* __restrict__ numout, int T) {
  int b = threadIdx.x;   // 64 threads
  const int* tg = tags + (size_t)b * T;
  int prev = tg[0];
  float num = start[prev] + logits[((size_t)b * T) * 16 + prev];
  for (int t = 1; t < T; ++t) {
    int cur = tg[t];
    num += trans[prev * 15 + cur] + logits[((size_t)b * T + t) * 16 + cur];
    prev = cur;
  }
  num += end[prev];
  numout[b] = num;
}

__global__ void crf_denom(const float* __restrict__ logits, const float* __restrict__ start,
                          const float* __restrict__ end, const float* __restrict__ trans,
                          float* __restrict__ denout, int T) {
  int b = blockIdx.x;
  int lane = threadIdx.x;              // 64 lanes, lanes >=15 mirror lane 0 (harmless)
  int kp = lane < 15 ? lane : 0;
  float tcol[15];
  #pragma unroll
  for (int k = 0; k < 15; ++k) tcol[k] = trans[k * 15 + kp];
  float score = start[kp] + logits[((size_t)b * T) * 16 + kp];
  for (int t = 1; t < T; ++t) {
    float e = logits[((size_t)b * T + t) * 16 + kp];
    float s[15], m = -3.4e38f;
    #pragma unroll
    for (int k = 0; k < 15; ++k) {
      s[k] = __shfl(score, k, 64) + tcol[k];
      m = fmaxf(m, s[k]);
    }
    float sum = 0.f;
    #pragma unroll
    for (int k = 0; k < 15; ++k) sum += __expf(s[k] - m);
    score = e + m + __logf(sum);
  }
  float x = score + end[kp];
  float m = -3.4e38f;
  #pragma unroll
  for (int k = 0; k < 15; ++k) m = fmaxf(m, __shfl(x, k, 64));
  float sum = 0.f;
  #pragma unroll
  for (int k = 0; k < 15; ++k) sum += __expf(__shfl(x, k, 64) - m);
  if (lane == 0) denout[b] = m + __logf(sum);
}

__global__ void crf_final(const float* __restrict__ num, const float* __restrict__ den,
                          float* __restrict__ out) {
  int l = threadIdx.x;   // 64
  float v = den[l] - num[l];
  #pragma unroll
  for (int off = 32; off > 0; off >>= 1) v += __shfl_xor(v, off, 64);
  if (l == 0) out[0] = v * (1.f / 64.f);
}

// ---------- host ----------
extern "C" void kernel_launch(void* const* d_in, const int* in_sizes, int n_in,
                              void* d_out, int out_size, void* d_ws, size_t ws_size,
                              hipStream_t stream) {
  const int B = 64, T = 512, M = B * T;   // 32768
  const float* we   = (const float*)d_in[1];
  const int*   cid  = (const int*)d_in[0];
  const int*   tags = (const int*)d_in[2];
  const float* etab = (const float*)d_in[3];

  char* ws = (char*)d_ws;
  size_t off = 0;
  auto alloc = [&](size_t bytes) -> char* {
    char* p = ws + off;
    off += (bytes + 255) & ~(size_t)255;
    return p;
  };
  unsigned short* wih_c0 = (unsigned short*)alloc((size_t)2048 * 128 * 2);
  unsigned short* wih_c1 = (unsigned short*)alloc((size_t)2048 * 512 * 2);
  unsigned short* wih_w0 = (unsigned short*)alloc((size_t)2048 * 768 * 2);
  unsigned short* wih_w1 = (unsigned short*)alloc((size_t)2048 * 512 * 2);
  unsigned short* cls1b  = (unsigned short*)alloc((size_t)512 * 1024 * 2);
  unsigned short* cls2b  = (unsigned short*)alloc((size_t)15 * 512 * 2);
  unsigned* whh_c0 = (unsigned*)alloc((size_t)262144 * 4);
  unsigned* whh_c1 = (unsigned*)alloc((size_t)262144 * 4);
  unsigned* whh_w0 = (unsigned*)alloc((size_t)262144 * 4);
  unsigned* whh_w1 = (unsigned*)alloc((size_t)262144 * 4);
  float* bs_c0 = (float*)alloc(2048 * 4);
  float* bs_c1 = (float*)alloc(2048 * 4);
  float* bs_w0 = (float*)alloc(2048 * 4);
  float* bs_w1 = (float*)alloc(2048 * 4);
  unsigned short* ce_b = (unsigned short*)alloc((size_t)M * 128 * 2);
  unsigned short* xg   = (unsigned short*)alloc((size_t)M * 2048 * 2);
  unsigned short* ch0  = (unsigned short*)alloc((size_t)M * 512 * 2);
  unsigned short* wh0  = (unsigned short*)alloc((size_t)M * 512 * 2);
  unsigned short* comb = (unsigned short*)alloc((size_t)M * 1024 * 2);
  unsigned short* h1   = (unsigned short*)alloc((size_t)M * 512 * 2);
  float* logits = (float*)alloc((size_t)M * 16 * 4);
  float* numb = (float*)alloc(64 * 4);
  float* denb = (float*)alloc(64 * 4);

  // ---- prep: weight conversions ----
  cvt_bf16<<<1024, 256, 0, stream>>>((const float*)d_in[4],  wih_c0, 2048 * 128);
  cvt_bf16<<<1024, 256, 0, stream>>>((const float*)d_in[8],  wih_c1, 2048 * 512);
  cvt_bf16<<<1024, 256, 0, stream>>>((const float*)d_in[12], wih_w0, 2048 * 768);
  cvt_bf16<<<1024, 256, 0, stream>>>((const float*)d_in[16], wih_w1, 2048 * 512);
  cvt_bf16<<<1024, 256, 0, stream>>>((const float*)d_in[20], cls1b, 512 * 1024);
  cvt_bf16<<<64, 256, 0, stream>>>((const float*)d_in[22], cls2b, 15 * 512);
  whh_pack<<<1024, 256, 0, stream>>>((const float*)d_in[5],  whh_c0);
  whh_pack<<<1024, 256, 0, stream>>>((const float*)d_in[9],  whh_c1);
  whh_pack<<<1024, 256, 0, stream>>>((const float*)d_in[13], whh_w0);
  whh_pack<<<1024, 256, 0, stream>>>((const float*)d_in[17], whh_w1);
  bias_sum<<<8, 256, 0, stream>>>((const float*)d_in[6],  (const float*)d_in[7],  bs_c0, 2048);
  bias_sum<<<8, 256, 0, stream>>>((const float*)d_in[10], (const float*)d_in[11], bs_c1, 2048);
  bias_sum<<<8, 256, 0, stream>>>((const float*)d_in[14], (const float*)d_in[15], bs_w0, 2048);
  bias_sum<<<8, 256, 0, stream>>>((const float*)d_in[18], (const float*)d_in[19], bs_w1, 2048);
  embed_gather<<<8192, 256, 0, stream>>>(cid, etab, ce_b, M * 128);

  // ---- char pathway ----
  gemm_bt<0, 0><<<512 * 32, 256, 0, stream>>>(ce_b, wih_c0, bs_c0, xg, M, 2048, 128);
  lstm_rec<<<128, 256, 0, stream>>>(whh_c0, xg, ch0, 512, 0, T);
  gemm_bt<0, 0><<<512 * 32, 256, 0, stream>>>(ch0, wih_c1, bs_c1, xg, M, 2048, 512);
  lstm_rec<<<128, 256, 0, stream>>>(whh_c1, xg, comb, 1024, 0, T);
  // ---- word pathway ----
  gemm_bt<0, 1><<<512 * 32, 256, 0, stream>>>(we, wih_w0, bs_w0, xg, M, 2048, 768);
  lstm_rec<<<128, 256, 0, stream>>>(whh_w0, xg, wh0, 512, 0, T);
  gemm_bt<0, 0><<<512 * 32, 256, 0, stream>>>(wh0, wih_w1, bs_w1, xg, M, 2048, 512);
  lstm_rec<<<128, 256, 0, stream>>>(whh_w1, xg, comb, 1024, 512, T);
  // ---- classifier ----
  gemm_bt<1, 0><<<512 * 8, 256, 0, stream>>>(comb, cls1b, (const float*)d_in[21], h1, M, 512, 1024);
  cls2_kernel<<<2048, 256, 0, stream>>>(h1, cls2b, (const float*)d_in[23], logits, M);
  // ---- CRF ----
  crf_num<<<1, 64, 0, stream>>>(logits, tags, (const float*)d_in[24], (const float*)d_in[25],
                                (const float*)d_in[26], numb, T);
  crf_denom<<<64, 64, 0, stream>>>(logits, (const float*)d_in[24], (const float*)d_in[25],
                                   (const float*)d_in[26], denb, T);
  crf_final<<<1, 64, 0, stream>>>(numb, denb, (float*)d_out);
}

// Round 3
// 15426.611 us; speedup vs baseline: 1.2309x; 1.2309x over previous
//
#include <hip/hip_runtime.h>

#define DEVI __device__ __forceinline__

typedef __attribute__((ext_vector_type(8))) __bf16 bf16x8;
typedef __attribute__((ext_vector_type(4))) float f32x4;

// ---------- scalar helpers ----------
DEVI unsigned short f2b(float f) {           // f32 -> bf16 (RNE)
  unsigned u = __float_as_uint(f);
  u = u + 0x7fffu + ((u >> 16) & 1u);
  return (unsigned short)(u >> 16);
}
DEVI float b2f(unsigned short h) { return __uint_as_float(((unsigned)h) << 16); }
DEVI float lo16(unsigned u) { return __uint_as_float(u << 16); }            // low bf16 of packed pair
DEVI float hi16(unsigned u) { return __uint_as_float(u & 0xffff0000u); }    // high bf16
DEVI float sigm(float x) { return 1.f / (1.f + __expf(-x)); }

// ---------- prep kernels ----------
__global__ void cvt_bf16(const float* __restrict__ in, unsigned short* __restrict__ out, int n) {
  for (int i = blockIdx.x * blockDim.x + threadIdx.x; i < n; i += gridDim.x * blockDim.x)
    out[i] = f2b(in[i]);
}

// Whh (2,1024,256) f32 -> packed uint out[d][kk][u][gate] = (bf16(W[d][g*256+u][2kk]), bf16(...2kk+1))
// idx = ((d*128+kk)*256+u)*4+gate  ->  kk = (idx&131071)>>10, u = (idx&1023)>>2, gate = idx&3
__global__ void whh_pack(const float* __restrict__ W, unsigned* __restrict__ out) {
  int idx = blockIdx.x * blockDim.x + threadIdx.x;   // 262144 total
  int d = idx >> 17, rem = idx & 131071;
  int kk = rem >> 10, rem2 = rem & 1023, u = rem2 >> 2, gate = rem2 & 3;
  const float* w = W + (((size_t)d * 1024 + gate * 256 + u) * 256 + 2 * kk);
  out[idx] = (unsigned)f2b(w[0]) | ((unsigned)f2b(w[1]) << 16);
}

__global__ void bias_sum(const float* __restrict__ a, const float* __restrict__ b,
                         float* __restrict__ o, int n) {
  int i = blockIdx.x * blockDim.x + threadIdx.x;
  if (i < n) o[i] = a[i] + b[i];
}

// char embedding gather: out[bt][c] = bf16(tab[ids[bt]][c]), CE=128
__global__ void embed_gather(const int* __restrict__ ids, const float* __restrict__ tab,
                             unsigned short* __restrict__ out, int total) {
  for (int i = blockIdx.x * blockDim.x + threadIdx.x; i < total; i += gridDim.x * blockDim.x) {
    int bt = i >> 7, c = i & 127;
    out[i] = f2b(tab[(size_t)ids[bt] * 128 + c]);
  }
}

// ---------- GEMM: C[M,N] = act(A[M,K] @ W[N,K]^T + bias[N]) -> bf16 ----------
// 64x64 tile, 4 waves, mfma_f32_16x16x32_bf16, operands straight from global (L2).
// PERM=1: output column remapped within each dir-half from gate*256+u to u*4+gate.
template <int ACT, int AFP32, int PERM>
__global__ __launch_bounds__(256) void gemm_bt(const void* __restrict__ Av,
                                               const unsigned short* __restrict__ W,
                                               const float* __restrict__ bias,
                                               unsigned short* __restrict__ C,
                                               int M, int N, int K) {
  const int ntiles = N >> 6;
  const int mt = blockIdx.x / ntiles;
  const int nt = blockIdx.x - mt * ntiles;
  const int m0 = mt << 6, n0 = nt << 6;
  const int tid = threadIdx.x;
  const int w = tid >> 6, lane = tid & 63, r = lane & 15, q = lane >> 4;
  f32x4 acc0 = {0.f, 0.f, 0.f, 0.f}, acc1 = acc0, acc2 = acc0, acc3 = acc0;
  const int arow = m0 + w * 16 + r;
  const unsigned short* Ab = (const unsigned short*)Av;
  const float* Af = (const float*)Av;
  for (int k0 = 0; k0 < K; k0 += 32) {
    const int ka = k0 + q * 8;
    bf16x8 a;
    if constexpr (AFP32) {
      const float* ap = Af + (size_t)arow * K + ka;
      float4 f0 = *(const float4*)ap;
      float4 f1 = *(const float4*)(ap + 4);
      union { unsigned short e[8]; bf16x8 v; } ua;
      ua.e[0] = f2b(f0.x); ua.e[1] = f2b(f0.y); ua.e[2] = f2b(f0.z); ua.e[3] = f2b(f0.w);
      ua.e[4] = f2b(f1.x); ua.e[5] = f2b(f1.y); ua.e[6] = f2b(f1.z); ua.e[7] = f2b(f1.w);
      a = ua.v;
    } else {
      a = *(const bf16x8*)(const void*)(Ab + (size_t)arow * K + ka);
    }
    const unsigned short* wb = W + (size_t)(n0 + r) * K + ka;
    bf16x8 b0 = *(const bf16x8*)(const void*)(wb);
    bf16x8 b1 = *(const bf16x8*)(const void*)(wb + (size_t)16 * K);
    bf16x8 b2 = *(const bf16x8*)(const void*)(wb + (size_t)32 * K);
    bf16x8 b3 = *(const bf16x8*)(const void*)(wb + (size_t)48 * K);
    acc0 = __builtin_amdgcn_mfma_f32_16x16x32_bf16(a, b0, acc0, 0, 0, 0);
    acc1 = __builtin_amdgcn_mfma_f32_16x16x32_bf16(a, b1, acc1, 0, 0, 0);
    acc2 = __builtin_amdgcn_mfma_f32_16x16x32_bf16(a, b2, acc2, 0, 0, 0);
    acc3 = __builtin_amdgcn_mfma_f32_16x16x32_bf16(a, b3, acc3, 0, 0, 0);
  }
  // D layout (m89-verified): col = lane&15, row = (lane>>4)*4 + reg
  const int rbase = m0 + w * 16 + q * 4;
  #pragma unroll
  for (int nb = 0; nb < 4; ++nb) {
    f32x4 acc = nb == 0 ? acc0 : nb == 1 ? acc1 : nb == 2 ? acc2 : acc3;
    const int col = n0 + nb * 16 + r;
    const float bv = bias[col];
    int oc = col;
    if constexpr (PERM) oc = (col & 1024) | ((col & 255) << 2) | ((col >> 8) & 3);
    #pragma unroll
    for (int i = 0; i < 4; ++i) {
      float v = acc[i] + bv;
      if constexpr (ACT) v = fmaxf(v, 0.f);
      C[(size_t)(rbase + i) * N + oc] = f2b(v);
    }
  }
}

// ---------- LSTM recurrence, 2 samples per block ----------
// 512 threads: u = tid&255 owns hidden unit u; half = tid>>8 covers kk in [half*64, half*64+64).
// Each thread accumulates gates for BOTH samples of its pair (weights loaded once).
// Weights: uint[128][256][4] per dir (kk-major, [u][gate] inner -> one uint4 per (kk,u)).
// xg: [B][T][2048] bf16, col = dir*1024 + u*4 + gate (PERM'd gemm output, bias included).
// Fused grid 128: grp = blockIdx>>6 selects pathway; rem&1 = dir; rem>>1 = sample pair.
__global__ __launch_bounds__(512) void lstm_rec(
    const unsigned* __restrict__ W0, const unsigned short* __restrict__ x0,
    unsigned short* __restrict__ o0, int os0, int oo0,
    const unsigned* __restrict__ W1, const unsigned short* __restrict__ x1,
    unsigned short* __restrict__ o1, int os1, int oo1, int T) {
  const int grp = blockIdx.x >> 6;
  const int rem = blockIdx.x & 63;
  const int dir = rem & 1, pr = rem >> 1;
  const int b0 = pr * 2;
  const int tid = threadIdx.x;
  const int u = tid & 255, half = tid >> 8;
  const unsigned* __restrict__ W2 = grp ? W1 : W0;
  const unsigned short* __restrict__ xg = grp ? x1 : x0;
  unsigned short* __restrict__ out = grp ? o1 : o0;
  const int outStride = grp ? os1 : os0;
  const int outOff = grp ? oo1 : oo0;

  __shared__ float hs[2][256];
  __shared__ float4 part[2][256];
  if (tid < 256) { hs[0][tid] = 0.f; hs[1][tid] = 0.f; }
  float c0 = 0.f, c1 = 0.f;
  const uint4* __restrict__ W4 = (const uint4*)(W2 + (size_t)dir * 131072);
  const unsigned short* xb0 = xg + (size_t)b0 * T * 2048 + dir * 1024 + u * 4;
  const unsigned short* xb1 = xb0 + (size_t)T * 2048;
  unsigned short* ob0 = out + (size_t)b0 * T * outStride + outOff + dir * 256 + u;
  unsigned short* ob1 = ob0 + (size_t)T * outStride;
  const uint4* __restrict__ wbase = W4 + (size_t)(half * 64) * 256 + u;
  const float2* __restrict__ h0base = (const float2*)&hs[0][half * 128];
  const float2* __restrict__ h1base = (const float2*)&hs[1][half * 128];
  __syncthreads();
  for (int ti = 0; ti < T; ++ti) {
    const int t = dir ? (T - 1 - ti) : ti;
    float gi0, gf0, gg0, go0, gi1, gf1, gg1, go1;
    if (half == 0) {
      uint2 xv0 = *(const uint2*)(xb0 + (size_t)t * 2048);
      uint2 xv1 = *(const uint2*)(xb1 + (size_t)t * 2048);
      gi0 = lo16(xv0.x); gf0 = hi16(xv0.x); gg0 = lo16(xv0.y); go0 = hi16(xv0.y);
      gi1 = lo16(xv1.x); gf1 = hi16(xv1.x); gg1 = lo16(xv1.y); go1 = hi16(xv1.y);
    } else {
      gi0 = gf0 = gg0 = go0 = 0.f;
      gi1 = gf1 = gg1 = go1 = 0.f;
    }
    #pragma unroll 8
    for (int kk = 0; kk < 64; ++kk) {
      const uint4 w4 = wbase[(size_t)kk * 256];
      const float2 ha = h0base[kk];    // broadcast, conflict-free
      const float2 hb = h1base[kk];
      const float wil = lo16(w4.x), wih = hi16(w4.x);
      const float wfl = lo16(w4.y), wfh = hi16(w4.y);
      const float wgl = lo16(w4.z), wgh = hi16(w4.z);
      const float wol = lo16(w4.w), woh = hi16(w4.w);
      gi0 = fmaf(ha.x, wil, gi0); gi0 = fmaf(ha.y, wih, gi0);
      gf0 = fmaf(ha.x, wfl, gf0); gf0 = fmaf(ha.y, wfh, gf0);
      gg0 = fmaf(ha.x, wgl, gg0); gg0 = fmaf(ha.y, wgh, gg0);
      go0 = fmaf(ha.x, wol, go0); go0 = fmaf(ha.y, woh, go0);
      gi1 = fmaf(hb.x, wil, gi1); gi1 = fmaf(hb.y, wih, gi1);
      gf1 = fmaf(hb.x, wfl, gf1); gf1 = fmaf(hb.y, wfh, gf1);
      gg1 = fmaf(hb.x, wgl, gg1); gg1 = fmaf(hb.y, wgh, gg1);
      go1 = fmaf(hb.x, wol, go1); go1 = fmaf(hb.y, woh, go1);
    }
    if (half) {
      part[0][u] = make_float4(gi0, gf0, gg0, go0);
      part[1][u] = make_float4(gi1, gf1, gg1, go1);
    }
    __syncthreads();                 // partials published; all hs reads done
    if (half == 0) {
      const float4 p0 = part[0][u];
      const float4 p1 = part[1][u];
      gi0 += p0.x; gf0 += p0.y; gg0 += p0.z; go0 += p0.w;
      gi1 += p1.x; gf1 += p1.y; gg1 += p1.z; go1 += p1.w;
      c0 = sigm(gf0) * c0 + sigm(gi0) * tanhf(gg0);
      c1 = sigm(gf1) * c1 + sigm(gi1) * tanhf(gg1);
      const float h0v = sigm(go0) * tanhf(c0);
      const float h1v = sigm(go1) * tanhf(c1);
      hs[0][u] = h0v;
      hs[1][u] = h1v;
      ob0[(size_t)t * outStride] = f2b(h0v);
      ob1[(size_t)t * outStride] = f2b(h1v);
    }
    __syncthreads();                 // new hs visible to all
  }
}

// ---------- classifier layer 2: logits[M,15] (stride 16) = h1[M,512] @ w2[15,512]^T + b2 ----------
__global__ __launch_bounds__(256) void cls2_kernel(const unsigned short* __restrict__ h1,
                                                   const unsigned short* __restrict__ w2,
                                                   const float* __restrict__ b2,
                                                   float* __restrict__ logits, int M) {
  int idx = blockIdx.x * 256 + threadIdx.x;
  int row = idx >> 4, n = idx & 15;
  if (row >= M || n >= 15) return;
  const unsigned* hp = (const unsigned*)(h1 + (size_t)row * 512);
  const unsigned* wp = (const unsigned*)(w2 + (size_t)n * 512);
  float acc = 0.f;
  #pragma unroll 8
  for (int k = 0; k < 256; ++k) {
    unsigned uh = hp[k], uw = wp[k];
    acc = fmaf(lo16(uh), lo16(uw), acc);
    acc = fmaf(hi16(uh), hi16(uw), acc);
  }
  logits[(size_t)row * 16 + n] = acc + b2[n];
}

// ---------- CRF ----------
__global__ void crf_num(const float* __restrict__ logits, const int* __restrict__ tags,
                        const float* __restrict__ start, const float* __restrict__ end,
                        const float* __restrict__ trans, float* __restrict__ numout, int T) {
  int b = threadIdx.x;   // 64 threads
  const int* tg = tags + (size_t)b * T;
  int prev = tg[0];
  float num = start[prev] + logits[((size_t)b * T) * 16 + prev];
  for (int t = 1; t < T; ++t) {
    int cur = tg[t];
    num += trans[prev * 15 + cur] + logits[((size_t)b * T + t) * 16 + cur];
    prev = cur;
  }
  num += end[prev];
  numout[b] = num;
}

__global__ void crf_denom(const float* __restrict__ logits, const float* __restrict__ start,
                          const float* __restrict__ end, const float* __restrict__ trans,
                          float* __restrict__ denout, int T) {
  int b = blockIdx.x;
  int lane = threadIdx.x;              // 64 lanes, lanes >=15 mirror lane 0 (harmless)
  int kp = lane < 15 ? lane : 0;
  float tcol[15];
  #pragma unroll
  for (int k = 0; k < 15; ++k) tcol[k] = trans[k * 15 + kp];
  float score = start[kp] + logits[((size_t)b * T) * 16 + kp];
  for (int t = 1; t < T; ++t) {
    float e = logits[((size_t)b * T + t) * 16 + kp];
    float s[15], m = -3.4e38f;
    #pragma unroll
    for (int k = 0; k < 15; ++k) {
      s[k] = __shfl(score, k, 64) + tcol[k];
      m = fmaxf(m, s[k]);
    }
    float sum = 0.f;
    #pragma unroll
    for (int k = 0; k < 15; ++k) sum += __expf(s[k] - m);
    score = e + m + __logf(sum);
  }
  float x = score + end[kp];
  float m = -3.4e38f;
  #pragma unroll
  for (int k = 0; k < 15; ++k) m = fmaxf(m, __shfl(x, k, 64));
  float sum = 0.f;
  #pragma unroll
  for (int k = 0; k < 15; ++k) sum += __expf(__shfl(x, k, 64) - m);
  if (lane == 0) denout[b] = m + __logf(sum);
}

__global__ void crf_final(const float* __restrict__ num, const float* __restrict__ den,
                          float* __restrict__ out) {
  int l = threadIdx.x;   // 64
  float v = den[l] - num[l];
  #pragma unroll
  for (int off = 32; off > 0; off >>= 1) v += __shfl_xor(v, off, 64);
  if (l == 0) out[0] = v * (1.f / 64.f);
}

// ---------- host ----------
extern "C" void kernel_launch(void* const* d_in, const int* in_sizes, int n_in,
                              void* d_out, int out_size, void* d_ws, size_t ws_size,
                              hipStream_t stream) {
  const int B = 64, T = 512, M = B * T;   // 32768
  const float* we   = (const float*)d_in[1];
  const int*   cid  = (const int*)d_in[0];
  const int*   tags = (const int*)d_in[2];
  const float* etab = (const float*)d_in[3];

  char* ws = (char*)d_ws;
  size_t off = 0;
  auto alloc = [&](size_t bytes) -> char* {
    char* p = ws + off;
    off += (bytes + 255) & ~(size_t)255;
    return p;
  };
  unsigned short* wih_c0 = (unsigned short*)alloc((size_t)2048 * 128 * 2);
  unsigned short* wih_c1 = (unsigned short*)alloc((size_t)2048 * 512 * 2);
  unsigned short* wih_w0 = (unsigned short*)alloc((size_t)2048 * 768 * 2);
  unsigned short* wih_w1 = (unsigned short*)alloc((size_t)2048 * 512 * 2);
  unsigned short* cls1b  = (unsigned short*)alloc((size_t)512 * 1024 * 2);
  unsigned short* cls2b  = (unsigned short*)alloc((size_t)15 * 512 * 2);
  unsigned* whh_c0 = (unsigned*)alloc((size_t)262144 * 4);
  unsigned* whh_c1 = (unsigned*)alloc((size_t)262144 * 4);
  unsigned* whh_w0 = (unsigned*)alloc((size_t)262144 * 4);
  unsigned* whh_w1 = (unsigned*)alloc((size_t)262144 * 4);
  float* bs_c0 = (float*)alloc(2048 * 4);
  float* bs_c1 = (float*)alloc(2048 * 4);
  float* bs_w0 = (float*)alloc(2048 * 4);
  float* bs_w1 = (float*)alloc(2048 * 4);
  unsigned short* ce_b = (unsigned short*)alloc((size_t)M * 128 * 2);
  unsigned short* ch0  = (unsigned short*)alloc((size_t)M * 512 * 2);
  unsigned short* wh0  = (unsigned short*)alloc((size_t)M * 512 * 2);
  unsigned short* comb = (unsigned short*)alloc((size_t)M * 1024 * 2);
  unsigned short* h1   = (unsigned short*)alloc((size_t)M * 512 * 2);
  float* logits = (float*)alloc((size_t)M * 16 * 4);
  float* numb = (float*)alloc(64 * 4);
  float* denb = (float*)alloc(64 * 4);
  unsigned short* xg_c = (unsigned short*)alloc((size_t)M * 2048 * 2);
  const size_t xgw_bytes = (size_t)M * 2048 * 2;
  const bool fused = (off + xgw_bytes) <= ws_size;
  unsigned short* xg_w = fused ? (unsigned short*)alloc(xgw_bytes) : xg_c;

  // ---- prep: weight conversions ----
  cvt_bf16<<<1024, 256, 0, stream>>>((const float*)d_in[4],  wih_c0, 2048 * 128);
  cvt_bf16<<<1024, 256, 0, stream>>>((const float*)d_in[8],  wih_c1, 2048 * 512);
  cvt_bf16<<<1024, 256, 0, stream>>>((const float*)d_in[12], wih_w0, 2048 * 768);
  cvt_bf16<<<1024, 256, 0, stream>>>((const float*)d_in[16], wih_w1, 2048 * 512);
  cvt_bf16<<<1024, 256, 0, stream>>>((const float*)d_in[20], cls1b, 512 * 1024);
  cvt_bf16<<<64, 256, 0, stream>>>((const float*)d_in[22], cls2b, 15 * 512);
  whh_pack<<<1024, 256, 0, stream>>>((const float*)d_in[5],  whh_c0);
  whh_pack<<<1024, 256, 0, stream>>>((const float*)d_in[9],  whh_c1);
  whh_pack<<<1024, 256, 0, stream>>>((const float*)d_in[13], whh_w0);
  whh_pack<<<1024, 256, 0, stream>>>((const float*)d_in[17], whh_w1);
  bias_sum<<<8, 256, 0, stream>>>((const float*)d_in[6],  (const float*)d_in[7],  bs_c0, 2048);
  bias_sum<<<8, 256, 0, stream>>>((const float*)d_in[10], (const float*)d_in[11], bs_c1, 2048);
  bias_sum<<<8, 256, 0, stream>>>((const float*)d_in[14], (const float*)d_in[15], bs_w0, 2048);
  bias_sum<<<8, 256, 0, stream>>>((const float*)d_in[18], (const float*)d_in[19], bs_w1, 2048);
  embed_gather<<<8192, 256, 0, stream>>>(cid, etab, ce_b, M * 128);

  if (fused) {
    // ---- level 0: both pathways ----
    gemm_bt<0, 0, 1><<<512 * 32, 256, 0, stream>>>(ce_b, wih_c0, bs_c0, xg_c, M, 2048, 128);
    gemm_bt<0, 1, 1><<<512 * 32, 256, 0, stream>>>(we, wih_w0, bs_w0, xg_w, M, 2048, 768);
    lstm_rec<<<128, 512, 0, stream>>>(whh_c0, xg_c, ch0, 512, 0,
                                      whh_w0, xg_w, wh0, 512, 0, T);
    // ---- level 1: both pathways ----
    gemm_bt<0, 0, 1><<<512 * 32, 256, 0, stream>>>(ch0, wih_c1, bs_c1, xg_c, M, 2048, 512);
    gemm_bt<0, 0, 1><<<512 * 32, 256, 0, stream>>>(wh0, wih_w1, bs_w1, xg_w, M, 2048, 512);
    lstm_rec<<<128, 512, 0, stream>>>(whh_c1, xg_c, comb, 1024, 0,
                                      whh_w1, xg_w, comb, 1024, 512, T);
  } else {
    gemm_bt<0, 0, 1><<<512 * 32, 256, 0, stream>>>(ce_b, wih_c0, bs_c0, xg_c, M, 2048, 128);
    lstm_rec<<<64, 512, 0, stream>>>(whh_c0, xg_c, ch0, 512, 0,
                                     whh_c0, xg_c, ch0, 512, 0, T);
    gemm_bt<0, 0, 1><<<512 * 32, 256, 0, stream>>>(ch0, wih_c1, bs_c1, xg_c, M, 2048, 512);
    lstm_rec<<<64, 512, 0, stream>>>(whh_c1, xg_c, comb, 1024, 0,
                                     whh_c1, xg_c, comb, 1024, 0, T);
    gemm_bt<0, 1, 1><<<512 * 32, 256, 0, stream>>>(we, wih_w0, bs_w0, xg_w, M, 2048, 768);
    lstm_rec<<<64, 512, 0, stream>>>(whh_w0, xg_w, wh0, 512, 0,
                                     whh_w0, xg_w, wh0, 512, 0, T);
    gemm_bt<0, 0, 1><<<512 * 32, 256, 0, stream>>>(wh0, wih_w1, bs_w1, xg_w, M, 2048, 512);
    lstm_rec<<<64, 512, 0, stream>>>(whh_w1, xg_w, comb, 1024, 512,
                                     whh_w1, xg_w, comb, 1024, 512, T);
  }
  // ---- classifier ----
  gemm_bt<1, 0, 0><<<512 * 8, 256, 0, stream>>>(comb, cls1b, (const float*)d_in[21], h1, M, 512, 1024);
  cls2_kernel<<<2048, 256, 0, stream>>>(h1, cls2b, (const float*)d_in[23], logits, M);
  // ---- CRF ----
  crf_num<<<1, 64, 0, stream>>>(logits, tags, (const float*)d_in[24], (const float*)d_in[25],
                                (const float*)d_in[26], numb, T);
  crf_denom<<<64, 64, 0, stream>>>(logits, (const float*)d_in[24], (const float*)d_in[25],
                                   (const float*)d_in[26], denb, T);
  crf_final<<<1, 64, 0, stream>>>(numb, denb, (float*)d_out);
}

// Round 4
// 7981.409 us; speedup vs baseline: 2.3790x; 1.9328x over previous
//
#include <hip/hip_runtime.h>

#define DEVI __device__ __forceinline__

typedef __attribute__((ext_vector_type(8))) __bf16 bf16x8;
typedef __attribute__((ext_vector_type(4))) float f32x4;
typedef __attribute__((ext_vector_type(2))) _Float16 half2_t;

// ---------- scalar helpers ----------
DEVI unsigned short f2b(float f) {           // f32 -> bf16 (RNE)
  unsigned u = __float_as_uint(f);
  u = u + 0x7fffu + ((u >> 16) & 1u);
  return (unsigned short)(u >> 16);
}
DEVI float b2f(unsigned short h) { return __uint_as_float(((unsigned)h) << 16); }
DEVI float lo16(unsigned u) { return __uint_as_float(u << 16); }
DEVI float hi16(unsigned u) { return __uint_as_float(u & 0xffff0000u); }
DEVI float sigm(float x) { return 1.f / (1.f + __expf(-x)); }
DEVI unsigned short f2h(float f) {
  union { _Float16 h; unsigned short u; } c; c.h = (_Float16)f; return c.u;
}
DEVI half2_t u2h(unsigned u) { return __builtin_bit_cast(half2_t, u); }

#if __has_builtin(__builtin_amdgcn_fdot2)
DEVI float dot2(unsigned h, unsigned w, float c) {   // c += h.x*w.x + h.y*w.y (fp16 pairs)
  return __builtin_amdgcn_fdot2(u2h(h), u2h(w), c, false);
}
#else
DEVI float dot2(unsigned h, unsigned w, float c) {
  half2_t a = u2h(h), b = u2h(w);
  c = fmaf((float)a.x, (float)b.x, c);
  return fmaf((float)a.y, (float)b.y, c);
}
#endif

// ---------- prep kernels ----------
__global__ void cvt_bf16(const float* __restrict__ in, unsigned short* __restrict__ out, int n) {
  for (int i = blockIdx.x * blockDim.x + threadIdx.x; i < n; i += gridDim.x * blockDim.x)
    out[i] = f2b(in[i]);
}

// Whh (2,1024,256) f32 -> packed fp16-pair uint out[d][kk][u][gate]
// idx = ((d*128+kk)*256+u)*4+gate
__global__ void whh_pack(const float* __restrict__ W, unsigned* __restrict__ out) {
  int idx = blockIdx.x * blockDim.x + threadIdx.x;   // 262144 total
  int d = idx >> 17, rem = idx & 131071;
  int kk = rem >> 10, rem2 = rem & 1023, u = rem2 >> 2, gate = rem2 & 3;
  const float* w = W + (((size_t)d * 1024 + gate * 256 + u) * 256 + 2 * kk);
  out[idx] = (unsigned)f2h(w[0]) | ((unsigned)f2h(w[1]) << 16);
}

__global__ void bias_sum(const float* __restrict__ a, const float* __restrict__ b,
                         float* __restrict__ o, int n) {
  int i = blockIdx.x * blockDim.x + threadIdx.x;
  if (i < n) o[i] = a[i] + b[i];
}

__global__ void embed_gather(const int* __restrict__ ids, const float* __restrict__ tab,
                             unsigned short* __restrict__ out, int total) {
  for (int i = blockIdx.x * blockDim.x + threadIdx.x; i < total; i += gridDim.x * blockDim.x) {
    int bt = i >> 7, c = i & 127;
    out[i] = f2b(tab[(size_t)ids[bt] * 128 + c]);
  }
}

// ---------- GEMM: C[M,N] = act(A[M,K](lda) @ W[N,K]^T + bias[N]) -> bf16 ----------
template <int ACT, int AFP32, int PERM>
__global__ __launch_bounds__(256) void gemm_bt(const void* __restrict__ Av, int lda,
                                               const unsigned short* __restrict__ W,
                                               const float* __restrict__ bias,
                                               unsigned short* __restrict__ C,
                                               int M, int N, int K) {
  const int ntiles = N >> 6;
  const int mt = blockIdx.x / ntiles;
  const int nt = blockIdx.x - mt * ntiles;
  const int m0 = mt << 6, n0 = nt << 6;
  const int tid = threadIdx.x;
  const int w = tid >> 6, lane = tid & 63, r = lane & 15, q = lane >> 4;
  f32x4 acc0 = {0.f, 0.f, 0.f, 0.f}, acc1 = acc0, acc2 = acc0, acc3 = acc0;
  const int arow = m0 + w * 16 + r;
  const unsigned short* Ab = (const unsigned short*)Av;
  const float* Af = (const float*)Av;
  for (int k0 = 0; k0 < K; k0 += 32) {
    const int ka = k0 + q * 8;
    bf16x8 a;
    if constexpr (AFP32) {
      const float* ap = Af + (size_t)arow * lda + ka;
      float4 f0 = *(const float4*)ap;
      float4 f1 = *(const float4*)(ap + 4);
      union { unsigned short e[8]; bf16x8 v; } ua;
      ua.e[0] = f2b(f0.x); ua.e[1] = f2b(f0.y); ua.e[2] = f2b(f0.z); ua.e[3] = f2b(f0.w);
      ua.e[4] = f2b(f1.x); ua.e[5] = f2b(f1.y); ua.e[6] = f2b(f1.z); ua.e[7] = f2b(f1.w);
      a = ua.v;
    } else {
      a = *(const bf16x8*)(const void*)(Ab + (size_t)arow * lda + ka);
    }
    const unsigned short* wb = W + (size_t)(n0 + r) * K + ka;
    bf16x8 b0 = *(const bf16x8*)(const void*)(wb);
    bf16x8 b1 = *(const bf16x8*)(const void*)(wb + (size_t)16 * K);
    bf16x8 b2 = *(const bf16x8*)(const void*)(wb + (size_t)32 * K);
    bf16x8 b3 = *(const bf16x8*)(const void*)(wb + (size_t)48 * K);
    acc0 = __builtin_amdgcn_mfma_f32_16x16x32_bf16(a, b0, acc0, 0, 0, 0);
    acc1 = __builtin_amdgcn_mfma_f32_16x16x32_bf16(a, b1, acc1, 0, 0, 0);
    acc2 = __builtin_amdgcn_mfma_f32_16x16x32_bf16(a, b2, acc2, 0, 0, 0);
    acc3 = __builtin_amdgcn_mfma_f32_16x16x32_bf16(a, b3, acc3, 0, 0, 0);
  }
  const int rbase = m0 + w * 16 + q * 4;
  #pragma unroll
  for (int nb = 0; nb < 4; ++nb) {
    f32x4 acc = nb == 0 ? acc0 : nb == 1 ? acc1 : nb == 2 ? acc2 : acc3;
    const int col = n0 + nb * 16 + r;
    const float bv = bias[col];
    int oc = col;
    if constexpr (PERM) oc = (col & 1024) | ((col & 255) << 2) | ((col >> 8) & 3);
    #pragma unroll
    for (int i = 0; i < 4; ++i) {
      float v = acc[i] + bv;
      if constexpr (ACT) v = fmaxf(v, 0.f);
      C[(size_t)(rbase + i) * N + oc] = f2b(v);
    }
  }
}

// ---------- LSTM recurrence, 2 samples per block, fp16 dot2 ----------
// 512 threads: u = tid&255 owns unit u; kh = tid>>8 covers kk half.
// Weights: uint[2][128][256][4] fp16 pairs. xg: [B][T][2048] bf16 col = dir*1024+u*4+gate.
// Grid 128 fused (grp = blockIdx>>6) or 64 single-pathway.
__global__ __launch_bounds__(512) void lstm_rec(
    const unsigned* __restrict__ W0, const unsigned short* __restrict__ x0,
    unsigned short* __restrict__ o0, int os0, int oo0,
    const unsigned* __restrict__ W1, const unsigned short* __restrict__ x1,
    unsigned short* __restrict__ o1, int os1, int oo1, int T) {
  const int grp = blockIdx.x >> 6;
  const int rem = blockIdx.x & 63;
  const int dir = rem & 1, pr = rem >> 1;
  const int b0 = pr * 2;
  const int tid = threadIdx.x;
  const int u = tid & 255, kh = tid >> 8;
  const unsigned* __restrict__ W2 = grp ? W1 : W0;
  const unsigned short* __restrict__ xg = grp ? x1 : x0;
  unsigned short* __restrict__ out = grp ? o1 : o0;
  const int outStride = grp ? os1 : os0;
  const int outOff = grp ? oo1 : oo0;

  __shared__ unsigned short hsu[2][256];   // fp16 h per sample
  __shared__ float4 part[2][256];
  if (tid < 256) { hsu[0][tid] = 0; hsu[1][tid] = 0; }
  float c0 = 0.f, c1 = 0.f;
  const uint4* __restrict__ W4 = (const uint4*)(W2 + (size_t)dir * 131072);
  const unsigned short* xb0 = xg + (size_t)b0 * T * 2048 + dir * 1024 + u * 4;
  const unsigned short* xb1 = xb0 + (size_t)T * 2048;
  unsigned short* ob0 = out + (size_t)b0 * T * outStride + outOff + dir * 256 + u;
  unsigned short* ob1 = ob0 + (size_t)T * outStride;
  const uint4* __restrict__ wbase = W4 + (size_t)(kh * 64) * 256 + u;
  const unsigned* __restrict__ h0base = (const unsigned*)&hsu[0][kh * 128];
  const unsigned* __restrict__ h1base = (const unsigned*)&hsu[1][kh * 128];
  __syncthreads();
  for (int ti = 0; ti < T; ++ti) {
    const int t = dir ? (T - 1 - ti) : ti;
    float gi0, gf0, gg0, go0, gi1, gf1, gg1, go1;
    if (kh == 0) {
      uint2 xv0 = *(const uint2*)(xb0 + (size_t)t * 2048);
      uint2 xv1 = *(const uint2*)(xb1 + (size_t)t * 2048);
      gi0 = lo16(xv0.x); gf0 = hi16(xv0.x); gg0 = lo16(xv0.y); go0 = hi16(xv0.y);
      gi1 = lo16(xv1.x); gf1 = hi16(xv1.x); gg1 = lo16(xv1.y); go1 = hi16(xv1.y);
    } else {
      gi0 = gf0 = gg0 = go0 = 0.f;
      gi1 = gf1 = gg1 = go1 = 0.f;
    }
    #pragma unroll 8
    for (int kk = 0; kk < 64; ++kk) {
      const uint4 w4 = wbase[(size_t)kk * 256];
      const unsigned ha = h0base[kk];      // broadcast, conflict-free
      const unsigned hb = h1base[kk];
      gi0 = dot2(ha, w4.x, gi0); gf0 = dot2(ha, w4.y, gf0);
      gg0 = dot2(ha, w4.z, gg0); go0 = dot2(ha, w4.w, go0);
      gi1 = dot2(hb, w4.x, gi1); gf1 = dot2(hb, w4.y, gf1);
      gg1 = dot2(hb, w4.z, gg1); go1 = dot2(hb, w4.w, go1);
    }
    if (kh) {
      part[0][u] = make_float4(gi0, gf0, gg0, go0);
      part[1][u] = make_float4(gi1, gf1, gg1, go1);
    }
    __syncthreads();                 // partials published; all hsu reads done
    if (kh == 0) {
      const float4 p0 = part[0][u];
      const float4 p1 = part[1][u];
      gi0 += p0.x; gf0 += p0.y; gg0 += p0.z; go0 += p0.w;
      gi1 += p1.x; gf1 += p1.y; gg1 += p1.z; go1 += p1.w;
      c0 = sigm(gf0) * c0 + sigm(gi0) * tanhf(gg0);
      c1 = sigm(gf1) * c1 + sigm(gi1) * tanhf(gg1);
      const float h0v = sigm(go0) * tanhf(c0);
      const float h1v = sigm(go1) * tanhf(c1);
      hsu[0][u] = f2h(h0v);
      hsu[1][u] = f2h(h1v);
      ob0[(size_t)t * outStride] = f2b(h0v);
      ob1[(size_t)t * outStride] = f2b(h1v);
    }
    __syncthreads();                 // new h visible to all
  }
}

// ---------- classifier layer 2 ----------
__global__ __launch_bounds__(256) void cls2_kernel(const unsigned short* __restrict__ h1,
                                                   const unsigned short* __restrict__ w2,
                                                   const float* __restrict__ b2,
                                                   float* __restrict__ logits, int M) {
  int idx = blockIdx.x * 256 + threadIdx.x;
  int row = idx >> 4, n = idx & 15;
  if (row >= M || n >= 15) return;
  const unsigned* hp = (const unsigned*)(h1 + (size_t)row * 512);
  const unsigned* wp = (const unsigned*)(w2 + (size_t)n * 512);
  float acc = 0.f;
  #pragma unroll 8
  for (int k = 0; k < 256; ++k) {
    unsigned uh = hp[k], uw = wp[k];
    acc = fmaf(lo16(uh), lo16(uw), acc);
    acc = fmaf(hi16(uh), hi16(uw), acc);
  }
  logits[(size_t)row * 16 + n] = acc + b2[n];
}

// ---------- CRF ----------
__global__ void crf_num(const float* __restrict__ logits, const int* __restrict__ tags,
                        const float* __restrict__ start, const float* __restrict__ end,
                        const float* __restrict__ trans, float* __restrict__ numout, int T) {
  int b = threadIdx.x;   // 64 threads
  const int* tg = tags + (size_t)b * T;
  int prev = tg[0];
  float num = start[prev] + logits[((size_t)b * T) * 16 + prev];
  for (int t = 1; t < T; ++t) {
    int cur = tg[t];
    num += trans[prev * 15 + cur] + logits[((size_t)b * T + t) * 16 + cur];
    prev = cur;
  }
  num += end[prev];
  numout[b] = num;
}

__global__ void crf_denom(const float* __restrict__ logits, const float* __restrict__ start,
                          const float* __restrict__ end, const float* __restrict__ trans,
                          float* __restrict__ denout, int T) {
  int b = blockIdx.x;
  int lane = threadIdx.x;
  int kp = lane < 15 ? lane : 0;
  float tcol[15];
  #pragma unroll
  for (int k = 0; k < 15; ++k) tcol[k] = trans[k * 15 + kp];
  float score = start[kp] + logits[((size_t)b * T) * 16 + kp];
  for (int t = 1; t < T; ++t) {
    float e = logits[((size_t)b * T + t) * 16 + kp];
    float s[15], m = -3.4e38f;
    #pragma unroll
    for (int k = 0; k < 15; ++k) {
      s[k] = __shfl(score, k, 64) + tcol[k];
      m = fmaxf(m, s[k]);
    }
    float sum = 0.f;
    #pragma unroll
    for (int k = 0; k < 15; ++k) sum += __expf(s[k] - m);
    score = e + m + __logf(sum);
  }
  float x = score + end[kp];
  float m = -3.4e38f;
  #pragma unroll
  for (int k = 0; k < 15; ++k) m = fmaxf(m, __shfl(x, k, 64));
  float sum = 0.f;
  #pragma unroll
  for (int k = 0; k < 15; ++k) sum += __expf(__shfl(x, k, 64) - m);
  if (lane == 0) denout[b] = m + __logf(sum);
}

__global__ void crf_final(const float* __restrict__ num, const float* __restrict__ den,
                          float* __restrict__ out) {
  int l = threadIdx.x;
  float v = den[l] - num[l];
  #pragma unroll
  for (int off = 32; off > 0; off >>= 1) v += __shfl_xor(v, off, 64);
  if (l == 0) out[0] = v * (1.f / 64.f);
}

// ---------- host ----------
extern "C" void kernel_launch(void* const* d_in, const int* in_sizes, int n_in,
                              void* d_out, int out_size, void* d_ws, size_t ws_size,
                              hipStream_t stream) {
  const int B = 64, T = 512, M = B * T;   // 32768
  const float* we   = (const float*)d_in[1];
  const int*   cid  = (const int*)d_in[0];
  const int*   tags = (const int*)d_in[2];
  const float* etab = (const float*)d_in[3];

  char* ws = (char*)d_ws;
  size_t off = 0;
  auto alloc = [&](size_t bytes) -> char* {
    char* p = ws + off;
    off += (bytes + 255) & ~(size_t)255;
    return p;
  };
  // small, permanent
  unsigned short* wih_c0 = (unsigned short*)alloc((size_t)2048 * 128 * 2);
  unsigned short* wih_c1 = (unsigned short*)alloc((size_t)2048 * 512 * 2);
  unsigned short* wih_w0 = (unsigned short*)alloc((size_t)2048 * 768 * 2);
  unsigned short* wih_w1 = (unsigned short*)alloc((size_t)2048 * 512 * 2);
  unsigned short* cls1b  = (unsigned short*)alloc((size_t)512 * 1024 * 2);
  unsigned short* cls2b  = (unsigned short*)alloc((size_t)15 * 512 * 2);
  unsigned* whh_c0 = (unsigned*)alloc((size_t)262144 * 4);
  unsigned* whh_c1 = (unsigned*)alloc((size_t)262144 * 4);
  unsigned* whh_w0 = (unsigned*)alloc((size_t)262144 * 4);
  unsigned* whh_w1 = (unsigned*)alloc((size_t)262144 * 4);
  float* bs_c0 = (float*)alloc(2048 * 4);
  float* bs_c1 = (float*)alloc(2048 * 4);
  float* bs_w0 = (float*)alloc(2048 * 4);
  float* bs_w1 = (float*)alloc(2048 * 4);
  float* numb = (float*)alloc(64 * 4);
  float* denb = (float*)alloc(64 * 4);
  // big
  unsigned short* comb = (unsigned short*)alloc((size_t)M * 1024 * 2);   // 64 MB
  unsigned short* xg_c = (unsigned short*)alloc((size_t)M * 2048 * 2);   // 128 MB
  const size_t xgw_bytes = (size_t)M * 2048 * 2;
  const bool fused = (off + xgw_bytes) <= ws_size;
  unsigned short* xg_w;
  unsigned short* ce_b;
  if (fused) {
    xg_w = (unsigned short*)alloc(xgw_bytes);
    ce_b = xg_w;                                   // gemm c0 consumes before gemm w0 writes
  } else {
    xg_w = xg_c;
    ce_b = (unsigned short*)alloc((size_t)M * 128 * 2);
  }
  unsigned short* h1 = xg_c;                        // free after level-1 lstm
  float* logits = (float*)(xg_c + (size_t)24 * 1024 * 1024);   // +48MB into xg_c

  // ---- prep ----
  cvt_bf16<<<1024, 256, 0, stream>>>((const float*)d_in[4],  wih_c0, 2048 * 128);
  cvt_bf16<<<1024, 256, 0, stream>>>((const float*)d_in[8],  wih_c1, 2048 * 512);
  cvt_bf16<<<1024, 256, 0, stream>>>((const float*)d_in[12], wih_w0, 2048 * 768);
  cvt_bf16<<<1024, 256, 0, stream>>>((const float*)d_in[16], wih_w1, 2048 * 512);
  cvt_bf16<<<1024, 256, 0, stream>>>((const float*)d_in[20], cls1b, 512 * 1024);
  cvt_bf16<<<64, 256, 0, stream>>>((const float*)d_in[22], cls2b, 15 * 512);
  whh_pack<<<1024, 256, 0, stream>>>((const float*)d_in[5],  whh_c0);
  whh_pack<<<1024, 256, 0, stream>>>((const float*)d_in[9],  whh_c1);
  whh_pack<<<1024, 256, 0, stream>>>((const float*)d_in[13], whh_w0);
  whh_pack<<<1024, 256, 0, stream>>>((const float*)d_in[17], whh_w1);
  bias_sum<<<8, 256, 0, stream>>>((const float*)d_in[6],  (const float*)d_in[7],  bs_c0, 2048);
  bias_sum<<<8, 256, 0, stream>>>((const float*)d_in[10], (const float*)d_in[11], bs_c1, 2048);
  bias_sum<<<8, 256, 0, stream>>>((const float*)d_in[14], (const float*)d_in[15], bs_w0, 2048);
  bias_sum<<<8, 256, 0, stream>>>((const float*)d_in[18], (const float*)d_in[19], bs_w1, 2048);
  embed_gather<<<8192, 256, 0, stream>>>(cid, etab, ce_b, M * 128);

  if (fused) {
    gemm_bt<0, 0, 1><<<512 * 32, 256, 0, stream>>>(ce_b, 128, wih_c0, bs_c0, xg_c, M, 2048, 128);
    gemm_bt<0, 1, 1><<<512 * 32, 256, 0, stream>>>(we, 768, wih_w0, bs_w0, xg_w, M, 2048, 768);
    lstm_rec<<<128, 512, 0, stream>>>(whh_c0, xg_c, comb, 1024, 0,
                                      whh_w0, xg_w, comb, 1024, 512, T);
    gemm_bt<0, 0, 1><<<512 * 32, 256, 0, stream>>>(comb, 1024, wih_c1, bs_c1, xg_c, M, 2048, 512);
    gemm_bt<0, 0, 1><<<512 * 32, 256, 0, stream>>>(comb + 512, 1024, wih_w1, bs_w1, xg_w, M, 2048, 512);
    lstm_rec<<<128, 512, 0, stream>>>(whh_c1, xg_c, comb, 1024, 0,
                                      whh_w1, xg_w, comb, 1024, 512, T);
  } else {
    gemm_bt<0, 0, 1><<<512 * 32, 256, 0, stream>>>(ce_b, 128, wih_c0, bs_c0, xg_c, M, 2048, 128);
    lstm_rec<<<64, 512, 0, stream>>>(whh_c0, xg_c, comb, 1024, 0,
                                     whh_c0, xg_c, comb, 1024, 0, T);
    gemm_bt<0, 0, 1><<<512 * 32, 256, 0, stream>>>(comb, 1024, wih_c1, bs_c1, xg_c, M, 2048, 512);
    lstm_rec<<<64, 512, 0, stream>>>(whh_c1, xg_c, comb, 1024, 0,
                                     whh_c1, xg_c, comb, 1024, 0, T);
    gemm_bt<0, 1, 1><<<512 * 32, 256, 0, stream>>>(we, 768, wih_w0, bs_w0, xg_c, M, 2048, 768);
    lstm_rec<<<64, 512, 0, stream>>>(whh_w0, xg_c, comb, 1024, 512,
                                     whh_w0, xg_c, comb, 1024, 512, T);
    gemm_bt<0, 0, 1><<<512 * 32, 256, 0, stream>>>(comb + 512, 1024, wih_w1, bs_w1, xg_c, M, 2048, 512);
    lstm_rec<<<64, 512, 0, stream>>>(whh_w1, xg_c, comb, 1024, 512,
                                     whh_w1, xg_c, comb, 1024, 512, T);
  }
  // ---- classifier ----
  gemm_bt<1, 0, 0><<<512 * 8, 256, 0, stream>>>(comb, 1024, cls1b, (const float*)d_in[21], h1, M, 512, 1024);
  cls2_kernel<<<2048, 256, 0, stream>>>(h1, cls2b, (const float*)d_in[23], logits, M);
  // ---- CRF ----
  crf_num<<<1, 64, 0, stream>>>(logits, tags, (const float*)d_in[24], (const float*)d_in[25],
                                (const float*)d_in[26], numb, T);
  crf_denom<<<64, 64, 0, stream>>>(logits, (const float*)d_in[24], (const float*)d_in[25],
                                   (const float*)d_in[26], denb, T);
  crf_final<<<1, 64, 0, stream>>>(numb, denb, (float*)d_out);
}